// Round 1
// baseline (1496.078 us; speedup 1.0000x reference)
//
#include <hip/hip_runtime.h>
#include <cstdint>
#include <cstddef>

#define BB 8
#define NN 1024
#define TT 8
#define CI 64
#define CO 64
#define BN_EPS 1e-5f

// ---------------- ws layout (floats) ----------------
// kp     : [T][CI][CO]           = 32768
// cmat   : [B][T][N][CO]         = 4194304
// escale : [B][T][N]             = 65536
// bns    : sum[64] + sumsq[64]   = 128
// total ~= 16.4 MB

// K0: repack k_tensor (CO,CI,T) -> kp[t][c][o]
__global__ __launch_bounds__(256) void k_pack(const float* __restrict__ k,
                                              float* __restrict__ kp) {
    int i = blockIdx.x * 256 + threadIdx.x;   // 32768 total
    int o = i & 63;
    int c = (i >> 6) & 63;
    int t = i >> 12;
    kp[i] = k[(o * CI + c) * TT + t];
}

// K1: per (b, 16-row chunk of m): rowsum -> w -> C_t = sfac * (w @ k_t^T), escale
__global__ __launch_bounds__(256) void k_prep(const float* __restrict__ points,
                                              const float* __restrict__ trans,
                                              const float* __restrict__ funcs,
                                              const float* __restrict__ kp,
                                              float* __restrict__ cmat,
                                              float* __restrict__ escale) {
    __shared__ float pts[NN * 3];      // all points of this batch
    __shared__ float ktl[CI * CO];     // k slice for current t, [c][o]
    __shared__ float wl[16 * CI];      // w rows for this chunk
    __shared__ float sfac[TT * 16];
    __shared__ float rpart[16 * 16];
    __shared__ float trl[TT * 3];
    __shared__ float tsql[TT];
    __shared__ float rsum[16];

    const int b = blockIdx.x & 7;               // XCD-swizzle: batch -> XCD
    const int m0 = (blockIdx.x >> 3) * 16;
    const int tid = threadIdx.x;

    for (int i = tid; i < NN * 3; i += 256) pts[i] = points[b * NN * 3 + i];
    if (tid < TT * 3) trl[tid] = trans[b * TT * 3 + tid];
    __syncthreads();

    if (tid < TT) {
        float x = trl[tid * 3], y = trl[tid * 3 + 1], z = trl[tid * 3 + 2];
        tsql[tid] = x * x + y * y + z * z;
    }
    // rowsum partials: 16 rows x 16 partial-sums (64 m-terms each)
    {
        const int ml = tid & 15, part = tid >> 4;
        const int n = m0 + ml;
        const float px = pts[n * 3], py = pts[n * 3 + 1], pz = pts[n * 3 + 2];
        const float sqn = px * px + py * py + pz * pz;
        float s = 0.f;
        for (int i = 0; i < 64; ++i) {
            int m2 = i * 16 + part;
            float qx = pts[m2 * 3], qy = pts[m2 * 3 + 1], qz = pts[m2 * 3 + 2];
            float d = sqn + qx * qx + qy * qy + qz * qz
                    - 2.f * (px * qx + py * qy + pz * qz);
            s += __expf(-0.5f * d);
        }
        rpart[ml * 16 + part] = s;
    }
    __syncthreads();
    if (tid < 16) {
        float s = 0.f;
        for (int p = 0; p < 16; ++p) s += rpart[tid * 16 + p];
        rsum[tid] = s;
    }
    __syncthreads();

    // w = functions / rowsum  (float4 per thread)
    {
        const int m = tid >> 4, c4 = (tid & 15) * 4;
        const float4 f = *(const float4*)&funcs[((size_t)(b * NN) + m0 + m) * CI + c4];
        const float inv = 1.f / rsum[m];
        *(float4*)&wl[m * CI + c4] = make_float4(f.x * inv, f.y * inv, f.z * inv, f.w * inv);
    }
    // scale factors: sfac = exp(-ptd - tsq/2), escale = exp(+ptd)
    if (tid < 128) {
        const int t = tid >> 4, m = tid & 15;
        const int n = m0 + m;
        const float px = pts[n * 3], py = pts[n * 3 + 1], pz = pts[n * 3 + 2];
        const float ptd = px * trl[t * 3] + py * trl[t * 3 + 1] + pz * trl[t * 3 + 2];
        sfac[t * 16 + m] = __expf(-ptd - 0.5f * tsql[t]);
        escale[(size_t)(b * TT + t) * NN + n] = __expf(ptd);
    }

    for (int t = 0; t < TT; ++t) {
        __syncthreads();   // protect ktl from previous iteration / ensure wl+sfac ready
        for (int i = tid; i < CI * CO; i += 256) ktl[i] = kp[t * CI * CO + i];
        __syncthreads();
        const int m = tid >> 4, o4 = (tid & 15) * 4;
        float4 acc = make_float4(0.f, 0.f, 0.f, 0.f);
        const float* wrow = &wl[m * CI];
        #pragma unroll 8
        for (int c = 0; c < CI; ++c) {
            float wv = wrow[c];
            float4 k4 = *(const float4*)&ktl[c * CO + o4];
            acc.x += wv * k4.x; acc.y += wv * k4.y;
            acc.z += wv * k4.z; acc.w += wv * k4.w;
        }
        const float sf = sfac[t * 16 + m];
        acc.x *= sf; acc.y *= sf; acc.z *= sf; acc.w *= sf;
        *(float4*)&cmat[((size_t)(b * TT + t) * NN + m0 + m) * CO + o4] = acc;
    }
}

// K2: out[b,n,o] = sum_t escale[t,n] * (G[b] @ C_t)[n,o]
// 256 blocks (b x 32 row-tiles), 512 threads. G tile [256 x 32] in LDS,
// computed once per K-quarter, reused across all 8 t.
__global__ __launch_bounds__(512) void k_main(const float* __restrict__ points,
                                              const float* __restrict__ cmat,
                                              const float* __restrict__ escale,
                                              float* __restrict__ out) {
    __shared__ float G[256 * 32];   // [mi][r]
    __shared__ float pn[32 * 3];
    __shared__ float sqn[32];
    __shared__ float pm[256 * 3];

    const int b = blockIdx.x & 7;               // XCD-swizzle
    const int n0 = (blockIdx.x >> 3) * 32;
    const int tid = threadIdx.x;
    const int r = tid >> 4;                     // 0..31 output row
    const int o4 = (tid & 15) * 4;              // output col group

    if (tid < 96) pn[tid] = points[((size_t)(b * NN) + n0) * 3 + tid];
    __syncthreads();
    if (tid < 32) {
        float x = pn[tid * 3], y = pn[tid * 3 + 1], z = pn[tid * 3 + 2];
        sqn[tid] = x * x + y * y + z * z;
    }

    float acc0 = 0.f, acc1 = 0.f, acc2 = 0.f, acc3 = 0.f;

    for (int q = 0; q < 4; ++q) {
        const int m0 = q * 256;
        __syncthreads();   // previous iteration done with G/pm (and sqn visible, q=0)
        for (int i = tid; i < 768; i += 512)
            pm[i] = points[((size_t)(b * NN) + m0) * 3 + i];
        __syncthreads();
        // build G tile: thread -> fixed row rr, 16 mi values
        {
            const int rr = tid & 31, mi0 = tid >> 5;   // mi0 in 0..15
            const float px = pn[rr * 3], py = pn[rr * 3 + 1], pz = pn[rr * 3 + 2];
            const float sq = sqn[rr];
            #pragma unroll
            for (int k = 0; k < 16; ++k) {
                int mi = mi0 + k * 16;
                float qx = pm[mi * 3], qy = pm[mi * 3 + 1], qz = pm[mi * 3 + 2];
                float d = sq + qx * qx + qy * qy + qz * qz
                        - 2.f * (px * qx + py * qy + pz * qz);
                G[mi * 32 + rr] = __expf(-0.5f * d);
            }
        }
        __syncthreads();

        for (int t = 0; t < TT; ++t) {
            float h0 = 0.f, h1 = 0.f, h2 = 0.f, h3 = 0.f;
            const float* cp = &cmat[((size_t)(b * TT + t) * NN + m0) * CO + o4];
            #pragma unroll 8
            for (int mi = 0; mi < 256; ++mi) {
                float g = G[mi * 32 + r];
                float4 c4 = *(const float4*)cp;
                cp += CO;
                h0 += g * c4.x; h1 += g * c4.y;
                h2 += g * c4.z; h3 += g * c4.w;
            }
            const float esc = escale[(size_t)(b * TT + t) * NN + n0 + r];
            acc0 += esc * h0; acc1 += esc * h1;
            acc2 += esc * h2; acc3 += esc * h3;
        }
    }
    *(float4*)&out[((size_t)(b * NN) + n0 + r) * CO + o4] =
        make_float4(acc0, acc1, acc2, acc3);
}

// K3: per-channel sum / sumsq partials -> atomics
__global__ __launch_bounds__(256) void k_stats(const float* __restrict__ out,
                                               float* __restrict__ bns) {
    __shared__ float s1[4][64], s2[4][64];
    const int tid = threadIdx.x;
    const int o = tid & 63, g = tid >> 6;
    const size_t base = (size_t)blockIdx.x * 64;   // 64 rows per block
    float a = 0.f, sq = 0.f;
    for (int i = 0; i < 16; ++i) {
        size_t row = base + g * 16 + i;
        float v = out[row * 64 + o];
        a += v; sq += v * v;
    }
    s1[g][o] = a; s2[g][o] = sq;
    __syncthreads();
    if (tid < 64) {
        float sa = s1[0][tid] + s1[1][tid] + s1[2][tid] + s1[3][tid];
        float sb = s2[0][tid] + s2[1][tid] + s2[2][tid] + s2[3][tid];
        atomicAdd(&bns[tid], sa);
        atomicAdd(&bns[64 + tid], sb);
    }
}

// K4: in-place BN (training stats) + ReLU
__global__ __launch_bounds__(256) void k_bn(float* __restrict__ out,
                                            const float* __restrict__ bns,
                                            const float* __restrict__ gamma,
                                            const float* __restrict__ beta) {
    const int i = blockIdx.x * 256 + threadIdx.x;   // one float4 each
    const int o4 = (i & 15) * 4;
    float4 x = ((float4*)out)[i];
    const float4 s  = *(const float4*)&bns[o4];
    const float4 s2 = *(const float4*)&bns[64 + o4];
    const float4 gm = *(const float4*)&gamma[o4];
    const float4 bt = *(const float4*)&beta[o4];
    const float invn = 1.f / 8192.f;
    float m, v, w;
    m = s.x * invn; v = s2.x * invn - m * m; w = __frsqrt_rn(v + BN_EPS) * gm.x;
    x.x = fmaxf((x.x - m) * w + bt.x, 0.f);
    m = s.y * invn; v = s2.y * invn - m * m; w = __frsqrt_rn(v + BN_EPS) * gm.y;
    x.y = fmaxf((x.y - m) * w + bt.y, 0.f);
    m = s.z * invn; v = s2.z * invn - m * m; w = __frsqrt_rn(v + BN_EPS) * gm.z;
    x.z = fmaxf((x.z - m) * w + bt.z, 0.f);
    m = s.w * invn; v = s2.w * invn - m * m; w = __frsqrt_rn(v + BN_EPS) * gm.w;
    x.w = fmaxf((x.w - m) * w + bt.w, 0.f);
    ((float4*)out)[i] = x;
}

extern "C" void kernel_launch(void* const* d_in, const int* in_sizes, int n_in,
                              void* d_out, int out_size, void* d_ws, size_t ws_size,
                              hipStream_t stream) {
    const float* points = (const float*)d_in[0];
    const float* trans  = (const float*)d_in[1];
    const float* funcs  = (const float*)d_in[2];
    const float* ktens  = (const float*)d_in[3];
    const float* gamma  = (const float*)d_in[4];
    const float* beta   = (const float*)d_in[5];
    float* out = (float*)d_out;

    float* ws     = (float*)d_ws;
    float* kp     = ws;                      // 32768
    float* cmat   = kp + 32768;              // 4194304
    float* escale = cmat + 4194304;          // 65536
    float* bns    = escale + 65536;          // 128

    hipMemsetAsync(bns, 0, 128 * sizeof(float), stream);
    k_pack<<<128, 256, 0, stream>>>(ktens, kp);
    k_prep<<<512, 256, 0, stream>>>(points, trans, funcs, kp, cmat, escale);
    k_main<<<256, 512, 0, stream>>>(points, cmat, escale, out);
    k_stats<<<128, 256, 0, stream>>>(out, bns);
    k_bn<<<512, 256, 0, stream>>>(out, bns, gamma, beta);
}

// Round 2
// 190.921 us; speedup vs baseline: 7.8361x; 7.8361x over previous
//
#include <hip/hip_runtime.h>
#include <hip/hip_bf16.h>
#include <cstdint>
#include <cstddef>

#define TT 8
#define CI 64
#define CO 64
#define BN_EPS 1e-5f

typedef float f32x4_t __attribute__((ext_vector_type(4)));
typedef __bf16 bf16x8_t __attribute__((ext_vector_type(8)));

__device__ __forceinline__ unsigned short f2bf(float f) {
    __hip_bfloat16 h = __float2bfloat16(f);
    return __builtin_bit_cast(unsigned short, h);
}
__device__ __forceinline__ float bf2f(unsigned short u) {
    unsigned int v = ((unsigned int)u) << 16;
    return __builtin_bit_cast(float, v);
}

// ---------------- ws layout ----------------
// kp     : float [T][CI][CO]            = 32768 f
// escale : float [B][T][N]              = 65536 f
// bns    : float sum[64]+sumsq[64]      = 128 f
// He     : bf16  [B][N][512]            = 4194304 us   (e-scaled G@Bmat)
// bmatT  : bf16  [B][512][N=1024(m)]    = 4194304 us
// total ~17.2 MB

// K0: repack k_tensor (CO,CI,T) -> kp[t][c][o]
__global__ __launch_bounds__(256) void k_pack(const float* __restrict__ k,
                                              float* __restrict__ kp) {
    int i = blockIdx.x * 256 + threadIdx.x;   // 32768 total
    int o = i & 63;
    int c = (i >> 6) & 63;
    int t = i >> 12;
    kp[i] = k[(o * CI + c) * TT + t];
}

// K1: per (b, 16-row chunk of m): rowsum -> w -> sfac*(w@k_t^T) -> bmatT (bf16,
// transposed via LDS), escale
__global__ __launch_bounds__(256) void k_prep(const float* __restrict__ points,
                                              const float* __restrict__ trans,
                                              const float* __restrict__ funcs,
                                              const float* __restrict__ kp,
                                              unsigned short* __restrict__ bmatT,
                                              float* __restrict__ escale) {
    __shared__ float pts[1024 * 3];
    __shared__ float ktl[CI * CO];
    __shared__ float wl[16 * CI];
    __shared__ float sfac[TT * 16];
    __shared__ float rpart[16 * 16];
    __shared__ float trl[TT * 3];
    __shared__ float tsql[TT];
    __shared__ float rsum[16];
    __shared__ unsigned short tile[512 * 16];   // [col=t*64+o][m]

    const int b = blockIdx.x & 7;
    const int m0 = (blockIdx.x >> 3) * 16;
    const int tid = threadIdx.x;

    for (int i = tid; i < 1024 * 3; i += 256) pts[i] = points[b * 1024 * 3 + i];
    if (tid < TT * 3) trl[tid] = trans[b * TT * 3 + tid];
    __syncthreads();

    if (tid < TT) {
        float x = trl[tid * 3], y = trl[tid * 3 + 1], z = trl[tid * 3 + 2];
        tsql[tid] = x * x + y * y + z * z;
    }
    {
        const int ml = tid & 15, part = tid >> 4;
        const int n = m0 + ml;
        const float px = pts[n * 3], py = pts[n * 3 + 1], pz = pts[n * 3 + 2];
        const float sqn = px * px + py * py + pz * pz;
        float s = 0.f;
        for (int i = 0; i < 64; ++i) {
            int m2 = i * 16 + part;
            float qx = pts[m2 * 3], qy = pts[m2 * 3 + 1], qz = pts[m2 * 3 + 2];
            float d = sqn + qx * qx + qy * qy + qz * qz
                    - 2.f * (px * qx + py * qy + pz * qz);
            s += __expf(-0.5f * d);
        }
        rpart[ml * 16 + part] = s;
    }
    __syncthreads();
    if (tid < 16) {
        float s = 0.f;
        for (int p = 0; p < 16; ++p) s += rpart[tid * 16 + p];
        rsum[tid] = s;
    }
    __syncthreads();

    {
        const int m = tid >> 4, c4 = (tid & 15) * 4;
        const float4 f = *(const float4*)&funcs[((size_t)(b * 1024) + m0 + m) * CI + c4];
        const float inv = 1.f / rsum[m];
        *(float4*)&wl[m * CI + c4] = make_float4(f.x * inv, f.y * inv, f.z * inv, f.w * inv);
    }
    if (tid < 128) {
        const int t = tid >> 4, m = tid & 15;
        const int n = m0 + m;
        const float px = pts[n * 3], py = pts[n * 3 + 1], pz = pts[n * 3 + 2];
        const float ptd = px * trl[t * 3] + py * trl[t * 3 + 1] + pz * trl[t * 3 + 2];
        sfac[t * 16 + m] = __expf(-ptd - 0.5f * tsql[t]);
        escale[(size_t)(b * TT + t) * 1024 + n] = __expf(ptd);
    }

    for (int t = 0; t < TT; ++t) {
        __syncthreads();
        for (int i = tid; i < CI * CO; i += 256) ktl[i] = kp[t * CI * CO + i];
        __syncthreads();
        const int m = tid >> 4, o4 = (tid & 15) * 4;
        float4 acc = make_float4(0.f, 0.f, 0.f, 0.f);
        const float* wrow = &wl[m * CI];
        #pragma unroll 8
        for (int c = 0; c < CI; ++c) {
            float wv = wrow[c];
            float4 k4 = *(const float4*)&ktl[c * CO + o4];
            acc.x += wv * k4.x; acc.y += wv * k4.y;
            acc.z += wv * k4.z; acc.w += wv * k4.w;
        }
        const float sf = sfac[t * 16 + m];
        tile[(t * 64 + o4 + 0) * 16 + m] = f2bf(acc.x * sf);
        tile[(t * 64 + o4 + 1) * 16 + m] = f2bf(acc.y * sf);
        tile[(t * 64 + o4 + 2) * 16 + m] = f2bf(acc.z * sf);
        tile[(t * 64 + o4 + 3) * 16 + m] = f2bf(acc.w * sf);
    }
    __syncthreads();
    // coalesced store: bmatT[b][col][m0..m0+15]
    for (int U = tid; U < 4096; U += 256) {
        int col = U >> 3, mp = U & 7;
        unsigned int val = (unsigned int)tile[col * 16 + 2 * mp]
                         | ((unsigned int)tile[col * 16 + 2 * mp + 1] << 16);
        *((unsigned int*)bmatT + ((size_t)(b * 512 + col) * 512 + (m0 >> 1) + mp)) = val;
    }
}

// K2: per batch H = G @ Bmat (M=1024,K=1024,N=512), epilogue *escale -> He bf16
// grid 256 = b(8) x rowtile(8,128 rows) x coltile(4,128 cols); 256 thr = 4 waves
__global__ __launch_bounds__(256) void k_gemm(const float* __restrict__ points,
                                              const unsigned short* __restrict__ bmatT,
                                              const float* __restrict__ escale,
                                              unsigned short* __restrict__ He) {
    __shared__ uint4 Af[2048];      // A frags: [rg(8)][s(4)][lane(64)] 16B
    __shared__ uint4 Bf[2048];      // B frags: [g(8)][s(4)][lane(64)] 16B
    __shared__ float pnlx[128], pnly[128], pnlz[128], sqnl[128];
    __shared__ float pklx[128], pkly[128], pklz[128], sqkl[128];
    __shared__ float escT[256];     // [wc(2)][row(128)]

    const int b  = blockIdx.x & 7;            // XCD swizzle
    const int rt = (blockIdx.x >> 3) & 7;
    const int ct = blockIdx.x >> 6;
    const int n0 = rt * 128;
    const int tid = threadIdx.x;
    const int wave = tid >> 6, lane = tid & 63;
    const int wr = wave >> 1, wc = wave & 1;

    if (tid < 128) {
        const float* p = &points[((size_t)(b * 1024) + n0 + tid) * 3];
        float x = p[0], y = p[1], z = p[2];
        pnlx[tid] = x; pnly[tid] = y; pnlz[tid] = z;
        sqnl[tid] = x * x + y * y + z * z;
    }
    if (tid < 256) escT[tid] = escale[(size_t)(b * 8 + ct * 2 + (tid >> 7)) * 1024 + n0 + (tid & 127)];

    f32x4_t acc[4][4];
    #pragma unroll
    for (int i = 0; i < 4; ++i)
        #pragma unroll
        for (int j = 0; j < 4; ++j) acc[i][j] = f32x4_t{0.f, 0.f, 0.f, 0.f};

    for (int kk = 0; kk < 8; ++kk) {
        const int k0 = kk * 128;
        // stage k-points (SoA + sq), computed by 2 waves
        if (tid < 128) {
            const float* p = &points[((size_t)(b * 1024) + k0 + tid) * 3];
            float x = p[0], y = p[1], z = p[2];
            pklx[tid] = x; pkly[tid] = y; pklz[tid] = z;
            sqkl[tid] = x * x + y * y + z * z;
        }
        // B tile loads into registers (overlap latency with A-build)
        uint4 breg[8];
        #pragma unroll
        for (int it = 0; it < 8; ++it) {
            int L = it * 256 + tid;
            int g = L >> 8, s = (L >> 6) & 3, l6 = L & 63;
            int n = l6 & 15, quad = l6 >> 4;
            int col = ct * 128 + g * 16 + n;
            int kq = k0 + s * 32 + quad * 8;
            breg[it] = *(const uint4*)(bmatT + ((size_t)(b * 512 + col) * 1024 + kq));
        }
        __syncthreads();   // pkl/sqkl visible; all waves done with prev Af/Bf
        // A-build: G chunk in fragment-major bf16
        #pragma unroll
        for (int it = 0; it < 8; ++it) {
            int L = it * 256 + tid;
            int rg = L >> 8, s = (L >> 6) & 3, l6 = L & 63;
            int m = l6 & 15, quad = l6 >> 4;
            int lr = rg * 16 + m;
            float px = pnlx[lr], py = pnly[lr], pz = pnlz[lr];
            float h = -0.5f * sqnl[lr];
            int kl = s * 32 + quad * 8;
            float4 x0 = *(const float4*)&pklx[kl], x1 = *(const float4*)&pklx[kl + 4];
            float4 y0 = *(const float4*)&pkly[kl], y1 = *(const float4*)&pkly[kl + 4];
            float4 z0 = *(const float4*)&pklz[kl], z1 = *(const float4*)&pklz[kl + 4];
            float4 s0 = *(const float4*)&sqkl[kl], s1 = *(const float4*)&sqkl[kl + 4];
            unsigned short us[8];
            {
                const float* xs = (const float*)&x0; const float* ys = (const float*)&y0;
                const float* zs = (const float*)&z0; const float* ss = (const float*)&s0;
                #pragma unroll
                for (int j = 0; j < 4; ++j) {
                    float dot = px * xs[j] + py * ys[j] + pz * zs[j];
                    us[j] = f2bf(__expf(h - 0.5f * ss[j] + dot));
                }
                xs = (const float*)&x1; ys = (const float*)&y1;
                zs = (const float*)&z1; ss = (const float*)&s1;
                #pragma unroll
                for (int j = 0; j < 4; ++j) {
                    float dot = px * xs[j] + py * ys[j] + pz * zs[j];
                    us[4 + j] = f2bf(__expf(h - 0.5f * ss[j] + dot));
                }
            }
            uint4 pk;
            pk.x = us[0] | ((unsigned int)us[1] << 16);
            pk.y = us[2] | ((unsigned int)us[3] << 16);
            pk.z = us[4] | ((unsigned int)us[5] << 16);
            pk.w = us[6] | ((unsigned int)us[7] << 16);
            Af[L] = pk;
        }
        #pragma unroll
        for (int it = 0; it < 8; ++it) Bf[it * 256 + tid] = breg[it];
        __syncthreads();   // Af/Bf visible
        // MFMA: wave (wr,wc) computes 64x64 via 4x4 tiles of 16x16
        #pragma unroll
        for (int s = 0; s < 4; ++s) {
            uint4 afr[4], bfr[4];
            #pragma unroll
            for (int i = 0; i < 4; ++i) afr[i] = Af[((wr * 4 + i) * 4 + s) * 64 + lane];
            #pragma unroll
            for (int j = 0; j < 4; ++j) bfr[j] = Bf[((wc * 4 + j) * 4 + s) * 64 + lane];
            #pragma unroll
            for (int i = 0; i < 4; ++i)
                #pragma unroll
                for (int j = 0; j < 4; ++j)
                    acc[i][j] = __builtin_amdgcn_mfma_f32_16x16x32_bf16(
                        __builtin_bit_cast(bf16x8_t, afr[i]),
                        __builtin_bit_cast(bf16x8_t, bfr[j]),
                        acc[i][j], 0, 0, 0);
        }
    }
    // epilogue: He[n][col] = e^{ptd[t,n]} * acc   (t == ct*2 + wc, uniform per wave)
    const int rquad = lane >> 4, cn = lane & 15;
    #pragma unroll
    for (int i = 0; i < 4; ++i) {
        #pragma unroll
        for (int r = 0; r < 4; ++r) {
            int lr = wr * 64 + i * 16 + rquad * 4 + r;
            float e = escT[wc * 128 + lr];
            size_t rowbase = ((size_t)(b * 1024) + n0 + lr) * 512;
            #pragma unroll
            for (int j = 0; j < 4; ++j) {
                int gcol = ct * 128 + wc * 64 + j * 16 + cn;
                He[rowbase + gcol] = f2bf(acc[i][j][r] * e);
            }
        }
    }
}

// K3: out[R,o] = sum_t He[R][t*64+o] ; fused BN partial sums
__global__ __launch_bounds__(256) void k_sum(const unsigned short* __restrict__ He,
                                             float* __restrict__ out,
                                             float* __restrict__ bns) {
    __shared__ float s1[16][64], s2[16][64];
    const int tid = threadIdx.x;
    const int row_l = tid >> 4, o4 = (tid & 15) * 4;
    const size_t R = (size_t)blockIdx.x * 16 + row_l;
    const unsigned short* hrow = He + R * 512 + o4;
    float a0 = 0.f, a1 = 0.f, a2 = 0.f, a3 = 0.f;
    #pragma unroll
    for (int t = 0; t < 8; ++t) {
        ushort4 u = *(const ushort4*)(hrow + t * 64);
        a0 += bf2f(u.x); a1 += bf2f(u.y); a2 += bf2f(u.z); a3 += bf2f(u.w);
    }
    *(float4*)(out + R * 64 + o4) = make_float4(a0, a1, a2, a3);
    *(float4*)&s1[row_l][o4] = make_float4(a0, a1, a2, a3);
    *(float4*)&s2[row_l][o4] = make_float4(a0 * a0, a1 * a1, a2 * a2, a3 * a3);
    __syncthreads();
    if (tid < 64) {
        float sa = 0.f, sb = 0.f;
        #pragma unroll
        for (int r2 = 0; r2 < 16; ++r2) { sa += s1[r2][tid]; sb += s2[r2][tid]; }
        atomicAdd(&bns[tid], sa);
        atomicAdd(&bns[64 + tid], sb);
    }
}

// K4: in-place BN (training stats) + ReLU
__global__ __launch_bounds__(256) void k_bn(float* __restrict__ out,
                                            const float* __restrict__ bns,
                                            const float* __restrict__ gamma,
                                            const float* __restrict__ beta) {
    const int i = blockIdx.x * 256 + threadIdx.x;
    const int o4 = (i & 15) * 4;
    float4 x = ((float4*)out)[i];
    const float4 s  = *(const float4*)&bns[o4];
    const float4 s2 = *(const float4*)&bns[64 + o4];
    const float4 gm = *(const float4*)&gamma[o4];
    const float4 bt = *(const float4*)&beta[o4];
    const float invn = 1.f / 8192.f;
    float m, v, w;
    m = s.x * invn; v = s2.x * invn - m * m; w = __frsqrt_rn(v + BN_EPS) * gm.x;
    x.x = fmaxf((x.x - m) * w + bt.x, 0.f);
    m = s.y * invn; v = s2.y * invn - m * m; w = __frsqrt_rn(v + BN_EPS) * gm.y;
    x.y = fmaxf((x.y - m) * w + bt.y, 0.f);
    m = s.z * invn; v = s2.z * invn - m * m; w = __frsqrt_rn(v + BN_EPS) * gm.z;
    x.z = fmaxf((x.z - m) * w + bt.z, 0.f);
    m = s.w * invn; v = s2.w * invn - m * m; w = __frsqrt_rn(v + BN_EPS) * gm.w;
    x.w = fmaxf((x.w - m) * w + bt.w, 0.f);
    ((float4*)out)[i] = x;
}

extern "C" void kernel_launch(void* const* d_in, const int* in_sizes, int n_in,
                              void* d_out, int out_size, void* d_ws, size_t ws_size,
                              hipStream_t stream) {
    const float* points = (const float*)d_in[0];
    const float* trans  = (const float*)d_in[1];
    const float* funcs  = (const float*)d_in[2];
    const float* ktens  = (const float*)d_in[3];
    const float* gamma  = (const float*)d_in[4];
    const float* beta   = (const float*)d_in[5];
    float* out = (float*)d_out;

    float* ws     = (float*)d_ws;
    float* kp     = ws;                          // 32768 f
    float* escale = kp + 32768;                  // 65536 f
    float* bns    = escale + 65536;              // 128 f
    unsigned short* He    = (unsigned short*)(bns + 128);   // 4194304 us
    unsigned short* bmatT = He + 4194304;                   // 4194304 us

    hipMemsetAsync(bns, 0, 128 * sizeof(float), stream);
    k_pack<<<128, 256, 0, stream>>>(ktens, kp);
    k_prep<<<512, 256, 0, stream>>>(points, trans, funcs, kp, bmatT, escale);
    k_gemm<<<256, 256, 0, stream>>>(points, bmatT, escale, He);
    k_sum<<<512, 256, 0, stream>>>(He, out, bns);
    k_bn<<<512, 256, 0, stream>>>(out, bns, gamma, beta);
}

// Round 3
// 148.900 us; speedup vs baseline: 10.0476x; 1.2822x over previous
//
#include <hip/hip_runtime.h>
#include <hip/hip_bf16.h>
#include <cstdint>
#include <cstddef>

#define BN_EPS 1e-5f

typedef float f32x4_t __attribute__((ext_vector_type(4)));
typedef __bf16 bf16x8_t __attribute__((ext_vector_type(8)));

__device__ __forceinline__ unsigned short f2bf(float f) {
    __hip_bfloat16 h = __float2bfloat16(f);
    return __builtin_bit_cast(unsigned short, h);
}
__device__ __forceinline__ float bf2f(unsigned short u) {
    unsigned int v = ((unsigned int)u) << 16;
    return __builtin_bit_cast(float, v);
}

// async global->LDS, 16B per lane. LDS dest must be (wave-uniform base + lane*16),
// which our tiling guarantees (lane l writes LDS bytes [base + 16l, base + 16l+16)).
__device__ __forceinline__ void gld_lds16(void* lds, const void* gp) {
#if __has_builtin(__builtin_amdgcn_global_load_lds)
    __builtin_amdgcn_global_load_lds(
        (const __attribute__((address_space(1))) unsigned int*)gp,
        (__attribute__((address_space(3))) unsigned int*)lds, 16, 0, 0);
#else
    *(uint4*)lds = *(const uint4*)gp;
#endif
}

// ---------------- ws layout ----------------
// kp     : float [T][CI][CO]              32768 f
// escale : float [B][T][N]                65536 f
// bns    : float sum[64]+sumsq[64]        128 f
// rowsum : float [B][N]                   8192 f
// He2    : float [8 part][B*N][64]        4194304 f   (16 MB)
// G      : bf16  [B][N][N]                8388608 us  (16 MB)
// bmatT  : bf16  [B][512 col][N(m)]       4194304 us  (8 MB)
// total ~42.4 MB

// K0: repack k_tensor (CO,CI,T) -> kp[t][c][o]
__global__ __launch_bounds__(256) void k_pack(const float* __restrict__ k,
                                              float* __restrict__ kp) {
    int i = blockIdx.x * 256 + threadIdx.x;   // 32768 total
    int o = i & 63;
    int c = (i >> 6) & 63;
    int t = i >> 12;
    kp[i] = k[(o * 64 + c) * 8 + t];
}

// K1: G[b][n][m] = exp(-dist/2) in bf16 (each exp computed exactly once),
// fused rowsum[b][n]. Block = (b, 32-row chunk). 256 blocks x 256 thr.
__global__ __launch_bounds__(256) void k_g(const float* __restrict__ points,
                                           unsigned short* __restrict__ G,
                                           float* __restrict__ rowsum) {
    __shared__ float praw[3072];
    __shared__ float px[1024], py[1024], pz[1024], hq[1024];
    __shared__ float rs[32];

    const int b = blockIdx.x & 7;               // XCD swizzle
    const int n0 = (blockIdx.x >> 3) * 32;
    const int tid = threadIdx.x;

    for (int i = tid; i < 3072; i += 256) praw[i] = points[b * 3072 + i];
    if (tid < 32) rs[tid] = 0.f;
    __syncthreads();
    for (int n = tid; n < 1024; n += 256) {
        float x = praw[n * 3], y = praw[n * 3 + 1], z = praw[n * 3 + 2];
        px[n] = x; py[n] = y; pz[n] = z;
        hq[n] = -0.5f * (x * x + y * y + z * z);
    }
    __syncthreads();

    const int rhalf = tid >> 7;                 // 0/1
    const int c0 = (tid & 127) * 8;
    unsigned short* gb = G + ((size_t)b << 20);

    for (int u = 0; u < 16; ++u) {
        const int rl = u * 2 + rhalf;           // local row 0..31
        const int row = n0 + rl;
        const float rx = px[row], ry = py[row], rz = pz[row], hr = hq[row];
        float vx[8], vy[8], vz[8], vh[8];
        *(float4*)&vx[0] = *(const float4*)&px[c0];
        *(float4*)&vx[4] = *(const float4*)&px[c0 + 4];
        *(float4*)&vy[0] = *(const float4*)&py[c0];
        *(float4*)&vy[4] = *(const float4*)&py[c0 + 4];
        *(float4*)&vz[0] = *(const float4*)&pz[c0];
        *(float4*)&vz[4] = *(const float4*)&pz[c0 + 4];
        *(float4*)&vh[0] = *(const float4*)&hq[c0];
        *(float4*)&vh[4] = *(const float4*)&hq[c0 + 4];
        unsigned short us[8];
        float ssum = 0.f;
        #pragma unroll
        for (int j = 0; j < 8; ++j) {
            float e = __expf(hr + vh[j] + rx * vx[j] + ry * vy[j] + rz * vz[j]);
            ssum += e;
            us[j] = f2bf(e);
        }
        uint4 pk;
        pk.x = us[0] | ((unsigned int)us[1] << 16);
        pk.y = us[2] | ((unsigned int)us[3] << 16);
        pk.z = us[4] | ((unsigned int)us[5] << 16);
        pk.w = us[6] | ((unsigned int)us[7] << 16);
        *(uint4*)(gb + (size_t)row * 1024 + c0) = pk;
        #pragma unroll
        for (int m = 32; m; m >>= 1) ssum += __shfl_xor(ssum, m, 64);
        if ((tid & 63) == 0) atomicAdd(&rs[rl], ssum);
    }
    __syncthreads();
    if (tid < 32) rowsum[b * 1024 + n0 + tid] = rs[tid];
}

// K2: light prep: w = funcs/rowsum; C_t = sfac*(w @ k_t^T) -> bmatT bf16; escale
__global__ __launch_bounds__(256) void k_prep(const float* __restrict__ points,
                                              const float* __restrict__ trans,
                                              const float* __restrict__ funcs,
                                              const float* __restrict__ kp,
                                              const float* __restrict__ rowsum,
                                              unsigned short* __restrict__ bmatT,
                                              float* __restrict__ escale) {
    __shared__ float ktl[4096];
    __shared__ float wl[16 * 64];
    __shared__ float sfac[8 * 16];
    __shared__ float trl[24];
    __shared__ float tsql[8];
    __shared__ float rsuml[16];
    __shared__ unsigned short tile[512 * 16];   // [col=t*64+o][m]

    const int b = blockIdx.x & 7;
    const int m0 = (blockIdx.x >> 3) * 16;
    const int tid = threadIdx.x;

    if (tid < 24) trl[tid] = trans[b * 24 + tid];
    if (tid < 16) rsuml[tid] = rowsum[b * 1024 + m0 + tid];
    __syncthreads();
    if (tid < 8) {
        float x = trl[tid * 3], y = trl[tid * 3 + 1], z = trl[tid * 3 + 2];
        tsql[tid] = x * x + y * y + z * z;
    }
    {
        const int m = tid >> 4, c4 = (tid & 15) * 4;
        const float4 f = *(const float4*)&funcs[((size_t)(b * 1024) + m0 + m) * 64 + c4];
        const float inv = 1.f / rsuml[m];
        *(float4*)&wl[m * 64 + c4] = make_float4(f.x * inv, f.y * inv, f.z * inv, f.w * inv);
    }
    __syncthreads();
    if (tid < 128) {
        const int t = tid >> 4, m = tid & 15;
        const int n = m0 + m;
        const float* pp = &points[(size_t)(b * 1024 + n) * 3];
        const float ptd = pp[0] * trl[t * 3] + pp[1] * trl[t * 3 + 1] + pp[2] * trl[t * 3 + 2];
        sfac[t * 16 + m] = __expf(-ptd - 0.5f * tsql[t]);
        escale[(size_t)(b * 8 + t) * 1024 + n] = __expf(ptd);
    }

    for (int t = 0; t < 8; ++t) {
        __syncthreads();
        for (int i = tid; i < 4096; i += 256) ktl[i] = kp[t * 4096 + i];
        __syncthreads();
        const int m = tid >> 4, o4 = (tid & 15) * 4;
        float4 acc = make_float4(0.f, 0.f, 0.f, 0.f);
        const float* wrow = &wl[m * 64];
        #pragma unroll 8
        for (int c = 0; c < 64; ++c) {
            float wv = wrow[c];
            float4 k4 = *(const float4*)&ktl[c * 64 + o4];
            acc.x += wv * k4.x; acc.y += wv * k4.y;
            acc.z += wv * k4.z; acc.w += wv * k4.w;
        }
        const float sf = sfac[t * 16 + m];
        tile[(t * 64 + o4 + 0) * 16 + m] = f2bf(acc.x * sf);
        tile[(t * 64 + o4 + 1) * 16 + m] = f2bf(acc.y * sf);
        tile[(t * 64 + o4 + 2) * 16 + m] = f2bf(acc.z * sf);
        tile[(t * 64 + o4 + 3) * 16 + m] = f2bf(acc.w * sf);
    }
    __syncthreads();
    for (int U = tid; U < 4096; U += 256) {
        int col = U >> 3, mp = U & 7;
        unsigned int val = (unsigned int)tile[col * 16 + 2 * mp]
                         | ((unsigned int)tile[col * 16 + 2 * mp + 1] << 16);
        *((unsigned int*)bmatT + ((size_t)(b * 512 + col) * 512 + (m0 >> 1) + mp)) = val;
    }
}

// K3: pure bf16 GEMM H = G @ Bmat with global_load_lds staging (m97 structure).
// grid 512 = b(8) x rt(8) x [ct(4) x kh(2)]; 256 thr = 4 waves; 128x128 tile, BK=32,
// K-half=512. Epilogue: *escale, reduce t-pair via LDS, write fp32 partial He2.
__global__ __launch_bounds__(256) void k_gemm(const unsigned short* __restrict__ G,
                                              const unsigned short* __restrict__ bmatT,
                                              const float* __restrict__ escale,
                                              float* __restrict__ He2) {
    __shared__ unsigned short As[4096];   // [row(128)][k(32)] bf16
    __shared__ unsigned short Bs[4096];   // [col(128)][k(32)] bf16
    __shared__ float red[128 * 65];       // padded reduce tile
    __shared__ float escT[256];           // [wc(2)][row(128)]

    const int b  = blockIdx.x & 7;        // XCD swizzle
    const int rt = (blockIdx.x >> 3) & 7;
    const int z  = blockIdx.x >> 6;       // 0..7
    const int ct = z & 3;
    const int kh = z >> 2;
    const int n0 = rt * 128;
    const int kb = kh * 512;

    const int tid  = threadIdx.x;
    const int wave = tid >> 6, lane = tid & 63;
    const int wr = wave >> 1, wc = wave & 1;

    escT[tid] = escale[(size_t)(b * 8 + ct * 2 + (tid >> 7)) * 1024 + n0 + (tid & 127)];

    const unsigned short* gA = G + ((size_t)b << 20) + (size_t)n0 * 1024 + kb;
    const unsigned short* gB = bmatT + (size_t)(b * 512 + ct * 128) * 1024 + kb;
    const size_t goff = (size_t)(lane >> 2) * 1024 + (lane & 3) * 8;   // ushort units

    f32x4_t acc[4][4];
    #pragma unroll
    for (int i = 0; i < 4; ++i)
        #pragma unroll
        for (int j = 0; j < 4; ++j) acc[i][j] = f32x4_t{0.f, 0.f, 0.f, 0.f};

    for (int kk = 0; kk < 16; ++kk) {
        const int k0 = kk * 32;
        __syncthreads();   // all waves done reading prev chunk's As/Bs
        #pragma unroll
        for (int i = 0; i < 2; ++i) {
            const int seg = wave * 2 + i;   // 16-row/col segment
            gld_lds16((char*)As + seg * 1024 + lane * 16,
                      gA + (size_t)(seg * 16) * 1024 + goff + k0);
            gld_lds16((char*)Bs + seg * 1024 + lane * 16,
                      gB + (size_t)(seg * 16) * 1024 + goff + k0);
        }
        __syncthreads();   // vmcnt drained pre-barrier -> tiles visible
        uint4 afr[4], bfr[4];
        #pragma unroll
        for (int i = 0; i < 4; ++i)
            afr[i] = *(const uint4*)((const char*)As
                     + (wr * 64 + i * 16 + (lane & 15)) * 64 + (lane >> 4) * 16);
        #pragma unroll
        for (int j = 0; j < 4; ++j)
            bfr[j] = *(const uint4*)((const char*)Bs
                     + (wc * 64 + j * 16 + (lane & 15)) * 64 + (lane >> 4) * 16);
        #pragma unroll
        for (int i = 0; i < 4; ++i)
            #pragma unroll
            for (int j = 0; j < 4; ++j)
                acc[i][j] = __builtin_amdgcn_mfma_f32_16x16x32_bf16(
                    __builtin_bit_cast(bf16x8_t, afr[i]),
                    __builtin_bit_cast(bf16x8_t, bfr[j]),
                    acc[i][j], 0, 0, 0);
    }

    // epilogue: scale by escale (t = ct*2 + wc), reduce wc-pair into red, store He2
    const int quad = lane >> 4, cn = lane & 15;
    if (wc == 0) {
        #pragma unroll
        for (int i = 0; i < 4; ++i)
            #pragma unroll
            for (int r = 0; r < 4; ++r) {
                const int row = wr * 64 + i * 16 + quad * 4 + r;
                const float e = escT[row];
                #pragma unroll
                for (int j = 0; j < 4; ++j)
                    red[row * 65 + j * 16 + cn] = acc[i][j][r] * e;
            }
    }
    __syncthreads();
    if (wc == 1) {
        #pragma unroll
        for (int i = 0; i < 4; ++i)
            #pragma unroll
            for (int r = 0; r < 4; ++r) {
                const int row = wr * 64 + i * 16 + quad * 4 + r;
                const float e = escT[128 + row];
                #pragma unroll
                for (int j = 0; j < 4; ++j)
                    red[row * 65 + j * 16 + cn] += acc[i][j][r] * e;
            }
    }
    __syncthreads();
    float4* dst = (float4*)(He2 + (size_t)(kh * 4 + ct) * 524288
                                + (size_t)(b * 1024 + n0) * 64);
    #pragma unroll
    for (int it = 0; it < 8; ++it) {
        const int L = it * 256 + tid;
        const int row = L >> 4, o4 = (L & 15) * 4;
        const float* rp = &red[row * 65 + o4];
        dst[L] = make_float4(rp[0], rp[1], rp[2], rp[3]);
    }
}

// K4: out = sum of 8 He2 partials; fused BN sum/sumsq
__global__ __launch_bounds__(256) void k_fin(const float* __restrict__ He2,
                                             float* __restrict__ out,
                                             float* __restrict__ bns) {
    __shared__ float s1[16][64], s2[16][64];
    const int tid = threadIdx.x;
    const float4* H4 = (const float4*)He2;
    float a0 = 0.f, a1 = 0.f, a2 = 0.f, a3 = 0.f;
    float q0 = 0.f, q1 = 0.f, q2 = 0.f, q3 = 0.f;
    #pragma unroll
    for (int it = 0; it < 2; ++it) {
        const size_t idx = (size_t)blockIdx.x * 512 + it * 256 + tid;
        float4 s = make_float4(0.f, 0.f, 0.f, 0.f);
        #pragma unroll
        for (int p = 0; p < 8; ++p) {
            float4 h = H4[(size_t)p * 131072 + idx];
            s.x += h.x; s.y += h.y; s.z += h.z; s.w += h.w;
        }
        ((float4*)out)[idx] = s;
        a0 += s.x; a1 += s.y; a2 += s.z; a3 += s.w;
        q0 += s.x * s.x; q1 += s.y * s.y; q2 += s.z * s.z; q3 += s.w * s.w;
    }
    const int g = tid >> 4, o4 = (tid & 15) * 4;
    *(float4*)&s1[g][o4] = make_float4(a0, a1, a2, a3);
    *(float4*)&s2[g][o4] = make_float4(q0, q1, q2, q3);
    __syncthreads();
    if (tid < 64) {
        float sa = 0.f, sb = 0.f;
        #pragma unroll
        for (int r = 0; r < 16; ++r) { sa += s1[r][tid]; sb += s2[r][tid]; }
        atomicAdd(&bns[tid], sa);
        atomicAdd(&bns[64 + tid], sb);
    }
}

// K5: in-place BN (training stats) + ReLU
__global__ __launch_bounds__(256) void k_bn(float* __restrict__ out,
                                            const float* __restrict__ bns,
                                            const float* __restrict__ gamma,
                                            const float* __restrict__ beta) {
    const int i = blockIdx.x * 256 + threadIdx.x;
    const int o4 = (i & 15) * 4;
    float4 x = ((float4*)out)[i];
    const float4 s  = *(const float4*)&bns[o4];
    const float4 s2 = *(const float4*)&bns[64 + o4];
    const float4 gm = *(const float4*)&gamma[o4];
    const float4 bt = *(const float4*)&beta[o4];
    const float invn = 1.f / 8192.f;
    float m, v, w;
    m = s.x * invn; v = s2.x * invn - m * m; w = __frsqrt_rn(v + BN_EPS) * gm.x;
    x.x = fmaxf((x.x - m) * w + bt.x, 0.f);
    m = s.y * invn; v = s2.y * invn - m * m; w = __frsqrt_rn(v + BN_EPS) * gm.y;
    x.y = fmaxf((x.y - m) * w + bt.y, 0.f);
    m = s.z * invn; v = s2.z * invn - m * m; w = __frsqrt_rn(v + BN_EPS) * gm.z;
    x.z = fmaxf((x.z - m) * w + bt.z, 0.f);
    m = s.w * invn; v = s2.w * invn - m * m; w = __frsqrt_rn(v + BN_EPS) * gm.w;
    x.w = fmaxf((x.w - m) * w + bt.w, 0.f);
    ((float4*)out)[i] = x;
}

extern "C" void kernel_launch(void* const* d_in, const int* in_sizes, int n_in,
                              void* d_out, int out_size, void* d_ws, size_t ws_size,
                              hipStream_t stream) {
    const float* points = (const float*)d_in[0];
    const float* trans  = (const float*)d_in[1];
    const float* funcs  = (const float*)d_in[2];
    const float* ktens  = (const float*)d_in[3];
    const float* gamma  = (const float*)d_in[4];
    const float* beta   = (const float*)d_in[5];
    float* out = (float*)d_out;

    float* ws      = (float*)d_ws;
    float* kp      = ws;                    // 32768 f
    float* escale  = kp + 32768;            // 65536 f
    float* bns     = escale + 65536;        // 128 f
    float* rowsum  = bns + 128;             // 8192 f
    float* He2     = rowsum + 8192;         // 4194304 f
    unsigned short* G     = (unsigned short*)(He2 + 4194304);   // 8388608 us
    unsigned short* bmatT = G + 8388608;                        // 4194304 us

    hipMemsetAsync(bns, 0, 128 * sizeof(float), stream);
    k_pack<<<128, 256, 0, stream>>>(ktens, kp);
    k_g<<<256, 256, 0, stream>>>(points, G, rowsum);
    k_prep<<<512, 256, 0, stream>>>(points, trans, funcs, kp, rowsum, bmatT, escale);
    k_gemm<<<512, 256, 0, stream>>>(G, bmatT, escale, He2);
    k_fin<<<256, 256, 0, stream>>>(He2, out, bns);
    k_bn<<<512, 256, 0, stream>>>(out, bns, gamma, beta);
}